// Round 18
// baseline (173.320 us; speedup 1.0000x reference)
//
#include <hip/hip_runtime.h>
#include <math.h>

#define NNODES 40000
#define CCH    128
#define NH     8
#define HD     16
#define NEDGE  640000
#define NBLK   157    // ceil(NNODES/256)
#define FBLK   10000  // k_fused blocks (4 waves each -> 40000 nodes)
#define RBLK   40     // k_reduce_part blocks
#define EBLK   625    // ceil(NEDGE/1024): 4 edges/thread kernels

typedef __attribute__((ext_vector_type(8))) short bf16x8;
typedef __attribute__((ext_vector_type(4))) float f32x4;
typedef __attribute__((ext_vector_type(2))) float f32x2;

__device__ inline unsigned short f2bf(float f) {
  union { float f; unsigned u; } c; c.f = f;
  unsigned r = c.u + 0x7fffu + ((c.u >> 16) & 1u);
  return (unsigned short)(r >> 16);
}
__device__ inline float bfs(unsigned short u) { union { unsigned i; float f; } c; c.i = (unsigned)u << 16; return c.f; }
__device__ inline float bflo(unsigned u) { union { unsigned i; float f; } c; c.i = u << 16; return c.f; }
__device__ inline float bfhi(unsigned u) { union { unsigned i; float f; } c; c.i = u & 0xffff0000u; return c.f; }

// ---- fp8 e4m3 (OCP) helpers ----
__device__ inline unsigned char f2fp8(float v) {
#if __has_builtin(__builtin_amdgcn_cvt_pk_fp8_f32)
  return (unsigned char)(__builtin_amdgcn_cvt_pk_fp8_f32(v, v, 0, false) & 0xff);
#else
  union { float f; unsigned u; } c; c.f = v;
  unsigned s = (c.u >> 24) & 0x80;
  int e = (int)((c.u >> 23) & 0xff) - 127;
  unsigned m = c.u & 0x7fffff;
  if (e > 8) return s | 0x7e;
  if (e >= -6) {
    unsigned q = (m + 0x80000) >> 20; unsigned ee = e + 7;
    if (q == 8) { q = 0; ee++; }
    if (ee > 15) return s | 0x7e;
    return s | (ee << 3) | q;
  }
  if (e < -10) return (unsigned char)s;
  float a = fabsf(v); unsigned q = (unsigned)(a * 512.f + 0.5f); if (q > 7) q = 7;
  return s | q;
#endif
}
__device__ inline void fp8x4d(unsigned w, float* o) {
#if __has_builtin(__builtin_amdgcn_cvt_pk_f32_fp8)
  f32x2 lo = __builtin_amdgcn_cvt_pk_f32_fp8((int)w, false);
  f32x2 hi = __builtin_amdgcn_cvt_pk_f32_fp8((int)w, true);
  o[0] = lo[0]; o[1] = lo[1]; o[2] = hi[0]; o[3] = hi[1];
#else
  #pragma unroll
  for (int i = 0; i < 4; i++) {
    unsigned b = (w >> (8 * i)) & 0xff;
    unsigned s = b >> 7, e = (b >> 3) & 15, m = b & 7;
    float v;
    if (e) { union { unsigned u; float f; } c; c.u = ((e + 120) << 23) | (m << 20); v = c.f; }
    else v = m * (1.f / 512.f);
    o[i] = s ? -v : v;
  }
#endif
}

// --- Combined weight prep (+deg zeroing): Wqkvt, W1t, W2t, Wot, bqkv ------
__global__ __launch_bounds__(256) void k_wprep_all(const float* __restrict__ Wq,
                                                   const float* __restrict__ Wk,
                                                   const float* __restrict__ Wv,
                                                   const float* __restrict__ W1,
                                                   const float* __restrict__ W2,
                                                   const float* __restrict__ Wo,
                                                   const float* __restrict__ bq,
                                                   const float* __restrict__ bk,
                                                   const float* __restrict__ bv,
                                                   unsigned short* __restrict__ Wqkvt,
                                                   unsigned short* __restrict__ W1t,
                                                   unsigned short* __restrict__ W2t,
                                                   unsigned short* __restrict__ Wot,
                                                   float* __restrict__ bqkv,
                                                   int* __restrict__ deg) {
  int g0 = blockIdx.x * 256 + threadIdx.x;
  if (g0 < NNODES) deg[g0] = 0;
  int idx = g0;
  if (idx < 16384) { int n = idx >> 7, k = idx & 127; Wqkvt[idx] = f2bf(Wq[(size_t)k * 128 + n]); return; }
  idx -= 16384;
  if (idx < 16384) { int n = idx >> 7, k = idx & 127; Wqkvt[16384 + (n << 7) + k] = f2bf(Wk[(size_t)k * 128 + n]); return; }
  idx -= 16384;
  if (idx < 16384) { int n = idx >> 7, k = idx & 127; Wqkvt[32768 + (n << 7) + k] = f2bf(Wv[(size_t)k * 128 + n]); return; }
  idx -= 16384;
  if (idx < 65536) { int n = idx >> 7, k = idx & 127; W1t[idx] = f2bf(W1[(size_t)k * 512 + n]); return; }
  idx -= 65536;
  if (idx < 65536) { int n = idx >> 9, k = idx & 511; W2t[idx] = f2bf(W2[(size_t)k * 128 + n]); return; }
  idx -= 65536;
  if (idx < 16384) { int n = idx >> 7, k = idx & 127; Wot[(n << 7) + k] = f2bf(Wo[(size_t)k * 128 + n]); return; }
  idx -= 16384;
  if (idx < 384) bqkv[idx] = idx < 128 ? bq[idx] : (idx < 256 ? bk[idx - 128] : bv[idx - 256]);
}

// ---- Stage-1 denominator reduce: hpart[10000][8] -> dpart[40][8] ----------
__global__ __launch_bounds__(256) void k_reduce_part(const float* __restrict__ hpart,
                                                     float* __restrict__ dpart) {
  const int t = threadIdx.x;
  const int h = t & 7;
  const int r0 = blockIdx.x * (FBLK / RBLK);
  float s = 0.f;
  for (int r = r0 + (t >> 3); r < r0 + FBLK / RBLK; r += 32) s += hpart[r * 8 + h];
  #pragma unroll
  for (int d = 8; d < 64; d <<= 1) s += __shfl_xor(s, d);
  __shared__ float ws4[4][8];
  int lane = t & 63, wv = t >> 6;
  if (lane < 8) ws4[wv][lane] = s;
  __syncthreads();
  if (t < 8) dpart[blockIdx.x * 8 + t] = ws4[0][t] + ws4[1][t] + ws4[2][t] + ws4[3][t];
}

// ------ K=128 GEMM, full A-tile resident. --------------------------------
// OUTMODE: 1 = bf16 out (NT col tiles in x-block), 2 = qkv-packed 512B rows.
// SPLITY: blockIdx.y picks ONE column tile (grid.y = NT); A-stage redundant.
template <int NT, int OUTMODE, bool LNA, bool RELU, bool SPLITY>
__global__ __launch_bounds__(256) void k_gemm128(const void* __restrict__ Ain,
                                                 const unsigned short* __restrict__ Bt,
                                                 const float* __restrict__ bias,
                                                 const float* __restrict__ lng,
                                                 const float* __restrict__ lnb,
                                                 void* __restrict__ outp) {
  __shared__ unsigned short As[64 * 128];   // 16 KB
  __shared__ unsigned short Bs[128 * 128];  // 32 KB
  const int tid  = threadIdx.x;
  const int row0 = blockIdx.x * 64;
  const int l    = tid & 63;
  const int w    = tid >> 6;
  const int wr   = w >> 1;
  const int wc   = w & 1;

  if (LNA) {
    const float* x = (const float*)Ain;
    int r = tid >> 2, qt = tid & 3;
    const float4* xr = (const float4*)(x + (size_t)(row0 + r) * 128 + qt * 32);
    float4 xv[8];
    float s = 0.f, ss = 0.f;
    #pragma unroll
    for (int i = 0; i < 8; i++) {
      xv[i] = xr[i];
      s  += xv[i].x + xv[i].y + xv[i].z + xv[i].w;
      ss += xv[i].x * xv[i].x + xv[i].y * xv[i].y + xv[i].z * xv[i].z + xv[i].w * xv[i].w;
    }
    s += __shfl_xor(s, 1); ss += __shfl_xor(ss, 1);
    s += __shfl_xor(s, 2); ss += __shfl_xor(ss, 2);
    float mean = s * (1.f / 128.f);
    float var  = ss * (1.f / 128.f) - mean * mean;
    float rstd = rsqrtf(var + 1e-5f);
    #pragma unroll
    for (int i = 0; i < 8; i += 2) {
      int c0 = qt * 32 + i * 4;
      float va[8] = {xv[i].x, xv[i].y, xv[i].z, xv[i].w,
                     xv[i+1].x, xv[i+1].y, xv[i+1].z, xv[i+1].w};
      unsigned short tmp[8];
      #pragma unroll
      for (int u = 0; u < 8; u++)
        tmp[u] = f2bf((va[u] - mean) * rstd * lng[c0 + u] + lnb[c0 + u]);
      int slot = c0 >> 3;
      *(uint4*)(As + r * 128 + ((slot ^ (r & 7)) * 8)) = *(uint4*)tmp;
    }
  } else {
    const unsigned short* A = (const unsigned short*)Ain;
    #pragma unroll
    for (int it = 0; it < 4; it++) {
      int idx = it * 256 + tid;
      int r = idx >> 4, sl = idx & 15;
      uint4 vv = *(const uint4*)(A + (size_t)(row0 + r) * 128 + sl * 8);
      *(uint4*)(As + r * 128 + ((sl ^ (r & 7)) * 8)) = vv;
    }
  }

  const int tBeg = SPLITY ? blockIdx.y : 0;
  const int tEnd = SPLITY ? blockIdx.y + 1 : NT;
  for (int t = tBeg; t < tEnd; t++) {
    __syncthreads();
    #pragma unroll
    for (int it = 0; it < 8; it++) {
      int idx = it * 256 + tid;
      int n = idx >> 4, sl = idx & 15;
      uint4 vv = *(const uint4*)(Bt + (size_t)(t * 128 + n) * 128 + sl * 8);
      *(uint4*)(Bs + n * 128 + ((sl ^ (n & 7)) * 8)) = vv;
    }
    __syncthreads();

    f32x4 acc[2][4] = {};
    #pragma unroll
    for (int kk = 0; kk < 4; kk++) {
      int sb = kk * 4 + (l >> 4);
      bf16x8 af[2], bfr[4];
      #pragma unroll
      for (int mi = 0; mi < 2; mi++) {
        int r = wr * 32 + mi * 16 + (l & 15);
        af[mi] = *(const bf16x8*)(As + r * 128 + ((sb ^ (r & 7)) * 8));
      }
      #pragma unroll
      for (int ni = 0; ni < 4; ni++) {
        int n = wc * 64 + ni * 16 + (l & 15);
        bfr[ni] = *(const bf16x8*)(Bs + n * 128 + ((sb ^ (n & 7)) * 8));
      }
      #pragma unroll
      for (int mi = 0; mi < 2; mi++)
        #pragma unroll
        for (int ni = 0; ni < 4; ni++)
          acc[mi][ni] = __builtin_amdgcn_mfma_f32_16x16x32_bf16(af[mi], bfr[ni], acc[mi][ni], 0, 0, 0);
    }

    #pragma unroll
    for (int mi = 0; mi < 2; mi++) {
      #pragma unroll
      for (int p = 0; p < 4; p++) {
        int r = row0 + wr * 32 + mi * 16 + (l >> 4) * 4 + p;
        #pragma unroll
        for (int ni = 0; ni < 4; ni++) {
          int cc = wc * 64 + ni * 16 + (l & 15);
          int c  = t * 128 + cc;
          float val = acc[mi][ni][p] + bias[c];
          if (RELU) val = fmaxf(val, 0.f);
          if (OUTMODE == 1) {
            ((unsigned short*)outp)[(size_t)r * (NT * 128) + c] = f2bf(val);
          } else {
            char* rowb = (char*)outp + (size_t)r * 512;
            if (t == 0)      *(unsigned short*)(rowb + cc * 2) = f2bf(val);
            else if (t == 1) *(unsigned char*)(rowb + 256 + cc) = f2fp8(val);
            else             *(unsigned char*)(rowb + 384 + cc) = f2fp8(val);
          }
        }
      }
    }
  }
}

// ---- Fused Wo-GEMM (inv-scaled A) + residual + LN2 + FFN1 ----------------
__global__ __launch_bounds__(256) void k_woln2ffn1(const unsigned short* __restrict__ agg,
                                                   const unsigned short* __restrict__ Wot,
                                                   const float* __restrict__ dpart,
                                                   const float* __restrict__ bo,
                                                   const float* __restrict__ x,
                                                   const float* __restrict__ lng,
                                                   const float* __restrict__ lnb,
                                                   const unsigned short* __restrict__ W1t,
                                                   const float* __restrict__ b1,
                                                   unsigned short* __restrict__ x1b,
                                                   unsigned short* __restrict__ ffn1) {
  __shared__ char arena[49152];
  unsigned short* As   = (unsigned short*)arena;
  unsigned short* Bs   = (unsigned short*)(arena + 8192);
  unsigned short* Fs   = (unsigned short*)arena;
  unsigned short* BsW1 = (unsigned short*)(arena + 16384);
  __shared__ float lnS[64][2], lnSS[64][2], gS[128], bS[128], sinv[8];

  const int tid  = threadIdx.x;
  const int row0 = blockIdx.x * 64;
  const int by   = blockIdx.y;
  const int l    = tid & 63;
  const int w    = tid >> 6;
  const int wr   = w >> 1;
  const int wc   = w & 1;

  {
    int h = tid & 7;
    float s = 0.f;
    for (int r = tid >> 3; r < RBLK; r += 32) s += dpart[r * 8 + h];
    #pragma unroll
    for (int d = 8; d < 64; d <<= 1) s += __shfl_xor(s, d);
    if (tid < 128) { gS[tid] = lng[tid]; bS[tid] = lnb[tid]; }
    __shared__ float ws4[4][8];
    int lane = tid & 63, wv = tid >> 6;
    if (lane < 8) ws4[wv][lane] = s;
    __syncthreads();
    if (tid < 8) sinv[tid] = 1.0f / (ws4[0][tid] + ws4[1][tid] + ws4[2][tid] + ws4[3][tid]);
  }

  f32x4 acc[2][4] = {};
  for (int kc = 0; kc < 128; kc += 64) {
    __syncthreads();
    #pragma unroll
    for (int it = 0; it < 2; it++) {
      int idx = it * 256 + tid;
      int r = idx >> 3, s5 = idx & 7;
      uint4 vv = *(const uint4*)(agg + (size_t)(row0 + r) * 128 + kc + s5 * 8);
      float sc = sinv[(kc >> 4) + (s5 >> 1)];
      unsigned short tmp[8];
      const unsigned short* pv = (const unsigned short*)&vv;
      #pragma unroll
      for (int u = 0; u < 8; u++) tmp[u] = f2bf(bfs(pv[u]) * sc);
      *(uint4*)(As + r * 64 + ((s5 ^ (r & 7)) * 8)) = *(uint4*)tmp;
    }
    #pragma unroll
    for (int it = 0; it < 4; it++) {
      int idx = it * 256 + tid;
      int n = idx >> 3, s5 = idx & 7;
      uint4 vv = *(const uint4*)(Wot + (size_t)n * 128 + kc + s5 * 8);
      *(uint4*)(Bs + n * 64 + ((s5 ^ (n & 7)) * 8)) = vv;
    }
    __syncthreads();
    #pragma unroll
    for (int kk = 0; kk < 2; kk++) {
      int sb = kk * 4 + (l >> 4);
      bf16x8 af[2], bfr[4];
      #pragma unroll
      for (int mi = 0; mi < 2; mi++) {
        int r = wr * 32 + mi * 16 + (l & 15);
        af[mi] = *(const bf16x8*)(As + r * 64 + ((sb ^ (r & 7)) * 8));
      }
      #pragma unroll
      for (int ni = 0; ni < 4; ni++) {
        int n = wc * 64 + ni * 16 + (l & 15);
        bfr[ni] = *(const bf16x8*)(Bs + n * 64 + ((sb ^ (n & 7)) * 8));
      }
      #pragma unroll
      for (int mi = 0; mi < 2; mi++)
        #pragma unroll
        for (int ni = 0; ni < 4; ni++)
          acc[mi][ni] = __builtin_amdgcn_mfma_f32_16x16x32_bf16(af[mi], bfr[ni], acc[mi][ni], 0, 0, 0);
    }
  }

  #pragma unroll
  for (int mi = 0; mi < 2; mi++) {
    #pragma unroll
    for (int p = 0; p < 4; p++) {
      int lr = wr * 32 + mi * 16 + (l >> 4) * 4 + p;
      int r  = row0 + lr;
      float s = 0.f, ss = 0.f;
      #pragma unroll
      for (int ni = 0; ni < 4; ni++) {
        int c = wc * 64 + ni * 16 + (l & 15);
        float val = acc[mi][ni][p] + bo[c] + x[(size_t)r * 128 + c];
        acc[mi][ni][p] = val;
        s += val; ss += val * val;
      }
      #pragma unroll
      for (int d = 1; d < 16; d <<= 1) { s += __shfl_xor(s, d); ss += __shfl_xor(ss, d); }
      if ((l & 15) == 0) { lnS[lr][wc] = s; lnSS[lr][wc] = ss; }
    }
  }
  __syncthreads();
  #pragma unroll
  for (int mi = 0; mi < 2; mi++) {
    #pragma unroll
    for (int p = 0; p < 4; p++) {
      int lr = wr * 32 + mi * 16 + (l >> 4) * 4 + p;
      int r  = row0 + lr;
      float m   = (lnS[lr][0] + lnS[lr][1]) * (1.f / 128.f);
      float var = (lnSS[lr][0] + lnSS[lr][1]) * (1.f / 128.f) - m * m;
      float rstd = rsqrtf(var + 1e-5f);
      #pragma unroll
      for (int ni = 0; ni < 4; ni++) {
        int c = wc * 64 + ni * 16 + (l & 15);
        float val = acc[mi][ni][p];
        if (by == 0) x1b[(size_t)r * 128 + c] = f2bf(val);
        unsigned short xb = f2bf((val - m) * rstd * gS[c] + bS[c]);
        Fs[lr * 128 + (((c >> 3) ^ (lr & 7)) * 8) + (c & 7)] = xb;
      }
    }
  }

  for (int ti = 0; ti < 2; ti++) {
    int t = by * 2 + ti;
    __syncthreads();
    #pragma unroll
    for (int it = 0; it < 8; it++) {
      int idx = it * 256 + tid;
      int n = idx >> 4, sl = idx & 15;
      uint4 vv = *(const uint4*)(W1t + (size_t)(t * 128 + n) * 128 + sl * 8);
      *(uint4*)(BsW1 + n * 128 + ((sl ^ (n & 7)) * 8)) = vv;
    }
    __syncthreads();

    f32x4 acc2[2][4] = {};
    #pragma unroll
    for (int kk = 0; kk < 4; kk++) {
      int sb = kk * 4 + (l >> 4);
      bf16x8 af[2], bfr[4];
      #pragma unroll
      for (int mi = 0; mi < 2; mi++) {
        int r = wr * 32 + mi * 16 + (l & 15);
        af[mi] = *(const bf16x8*)(Fs + r * 128 + ((sb ^ (r & 7)) * 8));
      }
      #pragma unroll
      for (int ni = 0; ni < 4; ni++) {
        int n = wc * 64 + ni * 16 + (l & 15);
        bfr[ni] = *(const bf16x8*)(BsW1 + n * 128 + ((sb ^ (n & 7)) * 8));
      }
      #pragma unroll
      for (int mi = 0; mi < 2; mi++)
        #pragma unroll
        for (int ni = 0; ni < 4; ni++)
          acc2[mi][ni] = __builtin_amdgcn_mfma_f32_16x16x32_bf16(af[mi], bfr[ni], acc2[mi][ni], 0, 0, 0);
    }

    #pragma unroll
    for (int mi = 0; mi < 2; mi++) {
      #pragma unroll
      for (int p = 0; p < 4; p++) {
        int r = row0 + wr * 32 + mi * 16 + (l >> 4) * 4 + p;
        #pragma unroll
        for (int ni = 0; ni < 4; ni++) {
          int cc = wc * 64 + ni * 16 + (l & 15);
          int c  = t * 128 + cc;
          float val = fmaxf(acc2[mi][ni][p] + b1[c], 0.f);
          ffn1[(size_t)r * 512 + c] = f2bf(val);
        }
      }
    }
  }
}

// ------ Generic MFMA GEMM (kc loop). Used for FFN2. -----------------------
template <bool RELU, int RESMODE>
__global__ __launch_bounds__(256) void k_mgemm(const unsigned short* __restrict__ A,
                                               const unsigned short* __restrict__ Bt,
                                               const float* __restrict__ bias,
                                               const void* __restrict__ res,
                                               float* __restrict__ outp,
                                               int K, int Nc) {
  __shared__ unsigned short As[64 * 64];
  __shared__ unsigned short Bs[128 * 64];
  const int tid  = threadIdx.x;
  const int row0 = blockIdx.x * 64;
  const int c0   = blockIdx.y * 128;
  const int l    = tid & 63;
  const int w    = tid >> 6;
  const int wr   = w >> 1;
  const int wc   = w & 1;

  f32x4 acc[2][4] = {};

  for (int kc = 0; kc < K; kc += 64) {
    __syncthreads();
    #pragma unroll
    for (int it = 0; it < 2; it++) {
      int idx = it * 256 + tid;
      int r = idx >> 3, s = idx & 7;
      uint4 vv = *(const uint4*)(A + (size_t)(row0 + r) * K + kc + s * 8);
      *(uint4*)(As + r * 64 + ((s ^ (r & 7)) * 8)) = vv;
    }
    #pragma unroll
    for (int it = 0; it < 4; it++) {
      int idx = it * 256 + tid;
      int n = idx >> 3, s = idx & 7;
      uint4 vv = *(const uint4*)(Bt + (size_t)(c0 + n) * K + kc + s * 8);
      *(uint4*)(Bs + n * 64 + ((s ^ (n & 7)) * 8)) = vv;
    }
    __syncthreads();
    #pragma unroll
    for (int kk = 0; kk < 2; kk++) {
      int sb = kk * 4 + (l >> 4);
      bf16x8 af[2], bfr[4];
      #pragma unroll
      for (int mi = 0; mi < 2; mi++) {
        int r = wr * 32 + mi * 16 + (l & 15);
        af[mi] = *(const bf16x8*)(As + r * 64 + ((sb ^ (r & 7)) * 8));
      }
      #pragma unroll
      for (int ni = 0; ni < 4; ni++) {
        int n = wc * 64 + ni * 16 + (l & 15);
        bfr[ni] = *(const bf16x8*)(Bs + n * 64 + ((sb ^ (n & 7)) * 8));
      }
      #pragma unroll
      for (int mi = 0; mi < 2; mi++)
        #pragma unroll
        for (int ni = 0; ni < 4; ni++)
          acc[mi][ni] = __builtin_amdgcn_mfma_f32_16x16x32_bf16(af[mi], bfr[ni], acc[mi][ni], 0, 0, 0);
    }
  }

  #pragma unroll
  for (int mi = 0; mi < 2; mi++) {
    #pragma unroll
    for (int p = 0; p < 4; p++) {
      int r = row0 + wr * 32 + mi * 16 + (l >> 4) * 4 + p;
      #pragma unroll
      for (int ni = 0; ni < 4; ni++) {
        int c = c0 + wc * 64 + ni * 16 + (l & 15);
        float val = acc[mi][ni][p] + bias[c];
        if (RESMODE == 1) val += ((const float*)res)[(size_t)r * Nc + c];
        if (RESMODE == 2) val += bfs(((const unsigned short*)res)[(size_t)r * Nc + c]);
        if (RELU) val = fmaxf(val, 0.f);
        outp[(size_t)r * Nc + c] = val;
      }
    }
  }
}

// ------- CSR build: hist+rank (4 edges/thread) -> scan -> scatter ----------
__global__ __launch_bounds__(256) void k_histrank(const int* __restrict__ ei,
                                                  int* __restrict__ deg,
                                                  int* __restrict__ rank) {
  int base = blockIdx.x * 1024 + threadIdx.x;
  #pragma unroll
  for (int u = 0; u < 4; u++) {
    int e = base + u * 256;
    if (e < NEDGE) rank[e] = atomicAdd(&deg[ei[NEDGE + e]], 1);
  }
}

__global__ __launch_bounds__(256) void k_scan3a(const int* __restrict__ deg,
                                                int* __restrict__ bsum) {
  int i = blockIdx.x * 256 + threadIdx.x;
  int d = (i < NNODES) ? deg[i] : 0;
  #pragma unroll
  for (int s = 1; s < 64; s <<= 1) d += __shfl_xor(d, s);
  __shared__ int ws4[4];
  if ((threadIdx.x & 63) == 0) ws4[threadIdx.x >> 6] = d;
  __syncthreads();
  if (threadIdx.x == 0) bsum[blockIdx.x] = ws4[0] + ws4[1] + ws4[2] + ws4[3];
}

__global__ __launch_bounds__(256) void k_scan3c(const int* __restrict__ deg,
                                                const int* __restrict__ bsum,
                                                int* __restrict__ off) {
  const int t = threadIdx.x;
  __shared__ int ws4[4];
  __shared__ int sbase;
  {
    int lim = blockIdx.x < NBLK ? blockIdx.x : NBLK;
    int v = (t < lim) ? bsum[t] : 0;
    #pragma unroll
    for (int s = 1; s < 64; s <<= 1) v += __shfl_xor(v, s);
    if ((t & 63) == 0) ws4[t >> 6] = v;
    __syncthreads();
    if (t == 0) sbase = ws4[0] + ws4[1] + ws4[2] + ws4[3];
    __syncthreads();
  }
  int i = blockIdx.x * 256 + t;
  int d = (i < NNODES) ? deg[i] : 0;
  int lane = t & 63, wv = t >> 6;
  int incl = d;
  #pragma unroll
  for (int s = 1; s < 64; s <<= 1) { int o = __shfl_up(incl, s); if (lane >= s) incl += o; }
  __syncthreads();
  if (lane == 63) ws4[wv] = incl;
  __syncthreads();
  int base = sbase;
  for (int w2 = 0; w2 < wv; w2++) base += ws4[w2];
  int ex = base + incl - d;
  if (i < NNODES) off[i] = ex;
  if (i == 0) off[NNODES] = NEDGE;
}

__global__ __launch_bounds__(256) void k_scatter(const int* __restrict__ ei,
                                                 const int* __restrict__ off,
                                                 const int* __restrict__ rank,
                                                 int* __restrict__ srcs) {
  int base = blockIdx.x * 1024 + threadIdx.x;
  #pragma unroll
  for (int u = 0; u < 4; u++) {
    int e = base + u * 256;
    if (e < NEDGE) srcs[off[ei[NEDGE + e]] + rank[e]] = ei[e];
  }
}

// ------- Fused scores + aggregation: 1 wave/node, 1 lane = 1 (edge,head) ---
__global__ __launch_bounds__(256) void k_fused(const unsigned char* __restrict__ qkv,
                                               const int* __restrict__ off,
                                               const int* __restrict__ srcs,
                                               unsigned* __restrict__ U,
                                               float* __restrict__ hpart) {
  const int wave = threadIdx.x >> 6;
  const int lane = threadIdx.x & 63;
  const int n  = blockIdx.x * 4 + wave;
  const int g  = lane >> 3;   // edge slot 0..7
  const int c8 = lane & 7;    // head; channels c8*16 .. +15

  const uint4* qp = (const uint4*)(qkv + (size_t)n * 512 + c8 * 32);
  uint4 qa = qp[0], qb = qp[1];
  float qf[16];
  qf[0]=bflo(qa.x);  qf[1]=bfhi(qa.x);  qf[2]=bflo(qa.y);  qf[3]=bfhi(qa.y);
  qf[4]=bflo(qa.z);  qf[5]=bfhi(qa.z);  qf[6]=bflo(qa.w);  qf[7]=bfhi(qa.w);
  qf[8]=bflo(qb.x);  qf[9]=bfhi(qb.x);  qf[10]=bflo(qb.y); qf[11]=bfhi(qb.y);
  qf[12]=bflo(qb.z); qf[13]=bfhi(qb.z); qf[14]=bflo(qb.w); qf[15]=bfhi(qb.w);

  float acc[16];
  #pragma unroll
  for (int i = 0; i < 16; i++) acc[i] = 0.f;
  float lsum = 0.f;

  const int i0 = off[n], i1 = off[n + 1];
  if (i1 > i0) {
    int j0 = i0 + g; if (j0 >= i1) j0 = i1 - 1;
    int sA = srcs[j0];
    int sB;
    {
      int j1 = i0 + 8 + g;
      if (j1 >= i1) j1 = i1 - 1;
      sB = srcs[j1];
    }
    const uint4* kpA = (const uint4*)(qkv + (size_t)sA * 512 + 256 + c8 * 16);
    uint4 kw = kpA[0], vw = kpA[8];

    for (int jb = i0; jb < i1; jb += 8) {
      uint4 kc = kw, vc = vw;
      bool valid = jb + g < i1;
      if (jb + 8 < i1) {
        const uint4* kpB = (const uint4*)(qkv + (size_t)sB * 512 + 256 + c8 * 16);
        kw = kpB[0]; vw = kpB[8];
      }
      if (jb + 16 < i1) {
        int j2 = jb + 16 + g;
        if (j2 >= i1) j2 = i1 - 1;
        sB = srcs[j2];
      }
      float kf[16], vf[16];
      fp8x4d(kc.x, kf + 0); fp8x4d(kc.y, kf + 4); fp8x4d(kc.z, kf + 8); fp8x4d(kc.w, kf + 12);
      fp8x4d(vc.x, vf + 0); fp8x4d(vc.y, vf + 4); fp8x4d(vc.z, vf + 8); fp8x4d(vc.w, vf + 12);
      float p = 0.f;
      #pragma unroll
      for (int i = 0; i < 16; i++) p += qf[i] * kf[i];
      float w = valid ? __expf(p * 0.25f) : 0.f;
      lsum += w;
      #pragma unroll
      for (int i = 0; i < 16; i++) acc[i] += w * vf[i];
    }
  }

  #pragma unroll
  for (int d = 8; d < 64; d <<= 1) {
    #pragma unroll
    for (int i = 0; i < 16; i++) acc[i] += __shfl_xor(acc[i], d);
    lsum += __shfl_xor(lsum, d);
  }

  __shared__ float wsum[4][8];
  if (lane < 8) {
    wsum[wave][c8] = lsum;
    unsigned o[8];
    #pragma unroll
    for (int i = 0; i < 8; i++)
      o[i] = ((unsigned)f2bf(acc[2 * i + 1]) << 16) | f2bf(acc[2 * i]);
    uint4* up = (uint4*)(U + (size_t)n * 64 + c8 * 8);
    up[0] = make_uint4(o[0], o[1], o[2], o[3]);
    up[1] = make_uint4(o[4], o[5], o[6], o[7]);
  }
  __syncthreads();
  if (threadIdx.x < 8) {
    hpart[blockIdx.x * 8 + threadIdx.x] =
        wsum[0][threadIdx.x] + wsum[1][threadIdx.x] + wsum[2][threadIdx.x] + wsum[3][threadIdx.x];
  }
}

extern "C" void kernel_launch(void* const* d_in, const int* in_sizes, int n_in,
                              void* d_out, int out_size, void* d_ws, size_t ws_size,
                              hipStream_t stream) {
  const float* x    = (const float*)d_in[0];
  const int*   ei   = (const int*)d_in[1];
  const float* Wq   = (const float*)d_in[2];
  const float* bq   = (const float*)d_in[3];
  const float* Wk   = (const float*)d_in[4];
  const float* bk   = (const float*)d_in[5];
  const float* Wv   = (const float*)d_in[6];
  const float* bv   = (const float*)d_in[7];
  const float* Wo   = (const float*)d_in[8];
  const float* bo   = (const float*)d_in[9];
  const float* ln1g = (const float*)d_in[10];
  const float* ln1b = (const float*)d_in[11];
  const float* ln2g = (const float*)d_in[12];
  const float* ln2b = (const float*)d_in[13];
  const float* W1   = (const float*)d_in[14];
  const float* b1   = (const float*)d_in[15];
  const float* W2   = (const float*)d_in[16];
  const float* b2   = (const float*)d_in[17];
  float* out = (float*)d_out;

  char* p = (char*)d_ws;
  const size_t NCb = (size_t)NNODES * CCH * 2;                  // 10.24 MB
  unsigned char*  qkvb = (unsigned char*)p;  p += (size_t)NNODES * 512;      // 20.48 MB
  unsigned short* agg  = (unsigned short*)p; p += NCb;                        // U
  unsigned short* x1b  = (unsigned short*)p; p += NCb;                        // x1 bf16
  unsigned short* ffn1 = (unsigned short*)p; p += (size_t)NNODES * 512 * 2;   // 40.96 MB
  int* deg    = (int*)p;                     p += (size_t)NNODES * 4 + 256;
  int* off    = (int*)p;                     p += (size_t)(NNODES + 1) * 4 + 256;
  int* rank   = (int*)p;                     p += (size_t)NEDGE * 4;
  int* srcs   = (int*)p;                     p += (size_t)NEDGE * 4;
  int* bsum   = (int*)p;                     p += 256 * 4;
  float* hpart = (float*)p;                  p += (size_t)FBLK * 8 * 4;
  float* dpart = (float*)p;                  p += (size_t)RBLK * 8 * 4 + 256;
  float* bqkv  = (float*)p;                  p += 384 * 4 + 256;
  unsigned short* Wqkvt = (unsigned short*)p; p += (size_t)384 * CCH * 2;
  unsigned short* Wot   = (unsigned short*)p; p += (size_t)CCH * CCH * 2;
  unsigned short* W1t   = (unsigned short*)p; p += (size_t)CCH * 4 * CCH * 2;
  unsigned short* W2t   = (unsigned short*)p; p += (size_t)CCH * 4 * CCH * 2;

  dim3 blk(256);
  dim3 gM(NNODES / 64, 1);
  dim3 gQ(NNODES / 64, 3);
  dim3 gW(NNODES / 64, 2);

  // 1. weight prep (incl. Wot) + deg zeroing
  k_wprep_all<<<770, blk, 0, stream>>>(Wq, Wk, Wv, W1, W2, Wo, bq, bk, bv,
                                       Wqkvt, W1t, W2t, Wot, bqkv, deg);

  // 2-5. CSR build (4 edges/thread)
  k_histrank<<<EBLK, blk, 0, stream>>>(ei, deg, rank);
  k_scan3a<<<NBLK, blk, 0, stream>>>(deg, bsum);
  k_scan3c<<<NBLK, blk, 0, stream>>>(deg, bsum, off);
  k_scatter<<<EBLK, blk, 0, stream>>>(ei, off, rank, srcs);

  // 6. LN1 + packed QKV GEMM fused, y-split: each y-block does one of q/k/v
  k_gemm128<3, 2, true, false, true><<<gQ, blk, 0, stream>>>(x, Wqkvt, bqkv,
                                                             ln1g, ln1b, qkvb);

  // 7-8. fused scores+aggregation, parallel denominator reduce
  k_fused<<<FBLK, blk, 0, stream>>>(qkvb, off, srcs, (unsigned*)agg, hpart);
  k_reduce_part<<<RBLK, blk, 0, stream>>>(hpart, dpart);

  // 9. fused Wo(inv-scaled A) + residual + LN2 + FFN1, y-split over 2 tiles
  k_woln2ffn1<<<gW, blk, 0, stream>>>(agg, Wot, dpart, bo, x, ln2g, ln2b,
                                      W1t, b1, x1b, ffn1);

  // 10. FFN2 (+bf16 residual x1) -> d_out fp32
  k_mgemm<false, 2><<<gM, blk, 0, stream>>>(ffn1, W2t, b2, x1b, out,
                                            4 * CCH, CCH);
}

// Round 19
// 153.774 us; speedup vs baseline: 1.1271x; 1.1271x over previous
//
#include <hip/hip_runtime.h>
#include <math.h>

#define NNODES 40000
#define CCH    128
#define NH     8
#define HD     16
#define NEDGE  640000
#define NBLK   157    // ceil(NNODES/256)
#define FBLK   10000  // k_fused blocks (4 waves each -> 40000 nodes)
#define RBLK   40     // k_reduce_part blocks
#define EBLK   625    // ceil(NEDGE/1024): 4 edges/thread kernels

typedef __attribute__((ext_vector_type(8))) short bf16x8;
typedef __attribute__((ext_vector_type(4))) float f32x4;
typedef __attribute__((ext_vector_type(2))) float f32x2;

__device__ inline unsigned short f2bf(float f) {
  union { float f; unsigned u; } c; c.f = f;
  unsigned r = c.u + 0x7fffu + ((c.u >> 16) & 1u);
  return (unsigned short)(r >> 16);
}
__device__ inline float bfs(unsigned short u) { union { unsigned i; float f; } c; c.i = (unsigned)u << 16; return c.f; }
__device__ inline float bflo(unsigned u) { union { unsigned i; float f; } c; c.i = u << 16; return c.f; }
__device__ inline float bfhi(unsigned u) { union { unsigned i; float f; } c; c.i = u & 0xffff0000u; return c.f; }

// ---- fp8 e4m3 (OCP) helpers ----
__device__ inline unsigned char f2fp8(float v) {
#if __has_builtin(__builtin_amdgcn_cvt_pk_fp8_f32)
  return (unsigned char)(__builtin_amdgcn_cvt_pk_fp8_f32(v, v, 0, false) & 0xff);
#else
  union { float f; unsigned u; } c; c.f = v;
  unsigned s = (c.u >> 24) & 0x80;
  int e = (int)((c.u >> 23) & 0xff) - 127;
  unsigned m = c.u & 0x7fffff;
  if (e > 8) return s | 0x7e;
  if (e >= -6) {
    unsigned q = (m + 0x80000) >> 20; unsigned ee = e + 7;
    if (q == 8) { q = 0; ee++; }
    if (ee > 15) return s | 0x7e;
    return s | (ee << 3) | q;
  }
  if (e < -10) return (unsigned char)s;
  float a = fabsf(v); unsigned q = (unsigned)(a * 512.f + 0.5f); if (q > 7) q = 7;
  return s | q;
#endif
}
__device__ inline void fp8x4d(unsigned w, float* o) {
#if __has_builtin(__builtin_amdgcn_cvt_pk_f32_fp8)
  f32x2 lo = __builtin_amdgcn_cvt_pk_f32_fp8((int)w, false);
  f32x2 hi = __builtin_amdgcn_cvt_pk_f32_fp8((int)w, true);
  o[0] = lo[0]; o[1] = lo[1]; o[2] = hi[0]; o[3] = hi[1];
#else
  #pragma unroll
  for (int i = 0; i < 4; i++) {
    unsigned b = (w >> (8 * i)) & 0xff;
    unsigned s = b >> 7, e = (b >> 3) & 15, m = b & 7;
    float v;
    if (e) { union { unsigned u; float f; } c; c.u = ((e + 120) << 23) | (m << 20); v = c.f; }
    else v = m * (1.f / 512.f);
    o[i] = s ? -v : v;
  }
#endif
}

// --- Combined weight prep (+deg zeroing): Wqkvt, W1t, W2t, Wot, bqkv ------
__global__ __launch_bounds__(256) void k_wprep_all(const float* __restrict__ Wq,
                                                   const float* __restrict__ Wk,
                                                   const float* __restrict__ Wv,
                                                   const float* __restrict__ W1,
                                                   const float* __restrict__ W2,
                                                   const float* __restrict__ Wo,
                                                   const float* __restrict__ bq,
                                                   const float* __restrict__ bk,
                                                   const float* __restrict__ bv,
                                                   unsigned short* __restrict__ Wqkvt,
                                                   unsigned short* __restrict__ W1t,
                                                   unsigned short* __restrict__ W2t,
                                                   unsigned short* __restrict__ Wot,
                                                   float* __restrict__ bqkv,
                                                   int* __restrict__ deg) {
  int g0 = blockIdx.x * 256 + threadIdx.x;
  if (g0 < NNODES) deg[g0] = 0;
  int idx = g0;
  if (idx < 16384) { int n = idx >> 7, k = idx & 127; Wqkvt[idx] = f2bf(Wq[(size_t)k * 128 + n]); return; }
  idx -= 16384;
  if (idx < 16384) { int n = idx >> 7, k = idx & 127; Wqkvt[16384 + (n << 7) + k] = f2bf(Wk[(size_t)k * 128 + n]); return; }
  idx -= 16384;
  if (idx < 16384) { int n = idx >> 7, k = idx & 127; Wqkvt[32768 + (n << 7) + k] = f2bf(Wv[(size_t)k * 128 + n]); return; }
  idx -= 16384;
  if (idx < 65536) { int n = idx >> 7, k = idx & 127; W1t[idx] = f2bf(W1[(size_t)k * 512 + n]); return; }
  idx -= 65536;
  if (idx < 65536) { int n = idx >> 9, k = idx & 511; W2t[idx] = f2bf(W2[(size_t)k * 128 + n]); return; }
  idx -= 65536;
  if (idx < 16384) { int n = idx >> 7, k = idx & 127; Wot[(n << 7) + k] = f2bf(Wo[(size_t)k * 128 + n]); return; }
  idx -= 16384;
  if (idx < 384) bqkv[idx] = idx < 128 ? bq[idx] : (idx < 256 ? bk[idx - 128] : bv[idx - 256]);
}

// ---- Stage-1 denominator reduce: hpart[10000][8] -> dpart[40][8] ----------
__global__ __launch_bounds__(256) void k_reduce_part(const float* __restrict__ hpart,
                                                     float* __restrict__ dpart) {
  const int t = threadIdx.x;
  const int h = t & 7;
  const int r0 = blockIdx.x * (FBLK / RBLK);
  float s = 0.f;
  for (int r = r0 + (t >> 3); r < r0 + FBLK / RBLK; r += 32) s += hpart[r * 8 + h];
  #pragma unroll
  for (int d = 8; d < 64; d <<= 1) s += __shfl_xor(s, d);
  __shared__ float ws4[4][8];
  int lane = t & 63, wv = t >> 6;
  if (lane < 8) ws4[wv][lane] = s;
  __syncthreads();
  if (t < 8) dpart[blockIdx.x * 8 + t] = ws4[0][t] + ws4[1][t] + ws4[2][t] + ws4[3][t];
}

// ------ K=128 GEMM, full A-tile resident, NT column tiles per block. ------
// OUTMODE: 1 = bf16 out, 2 = qkv-packed 512B rows (NT=3). LNA: LN fused A.
template <int NT, int OUTMODE, bool LNA, bool RELU>
__global__ __launch_bounds__(256) void k_gemm128(const void* __restrict__ Ain,
                                                 const unsigned short* __restrict__ Bt,
                                                 const float* __restrict__ bias,
                                                 const float* __restrict__ lng,
                                                 const float* __restrict__ lnb,
                                                 void* __restrict__ outp) {
  __shared__ unsigned short As[64 * 128];   // 16 KB
  __shared__ unsigned short Bs[128 * 128];  // 32 KB
  const int tid  = threadIdx.x;
  const int row0 = blockIdx.x * 64;
  const int l    = tid & 63;
  const int w    = tid >> 6;
  const int wr   = w >> 1;
  const int wc   = w & 1;

  if (LNA) {
    const float* x = (const float*)Ain;
    int r = tid >> 2, qt = tid & 3;
    const float4* xr = (const float4*)(x + (size_t)(row0 + r) * 128 + qt * 32);
    float4 xv[8];
    float s = 0.f, ss = 0.f;
    #pragma unroll
    for (int i = 0; i < 8; i++) {
      xv[i] = xr[i];
      s  += xv[i].x + xv[i].y + xv[i].z + xv[i].w;
      ss += xv[i].x * xv[i].x + xv[i].y * xv[i].y + xv[i].z * xv[i].z + xv[i].w * xv[i].w;
    }
    s += __shfl_xor(s, 1); ss += __shfl_xor(ss, 1);
    s += __shfl_xor(s, 2); ss += __shfl_xor(ss, 2);
    float mean = s * (1.f / 128.f);
    float var  = ss * (1.f / 128.f) - mean * mean;
    float rstd = rsqrtf(var + 1e-5f);
    #pragma unroll
    for (int i = 0; i < 8; i += 2) {
      int c0 = qt * 32 + i * 4;
      float va[8] = {xv[i].x, xv[i].y, xv[i].z, xv[i].w,
                     xv[i+1].x, xv[i+1].y, xv[i+1].z, xv[i+1].w};
      unsigned short tmp[8];
      #pragma unroll
      for (int u = 0; u < 8; u++)
        tmp[u] = f2bf((va[u] - mean) * rstd * lng[c0 + u] + lnb[c0 + u]);
      int slot = c0 >> 3;
      *(uint4*)(As + r * 128 + ((slot ^ (r & 7)) * 8)) = *(uint4*)tmp;
    }
  } else {
    const unsigned short* A = (const unsigned short*)Ain;
    #pragma unroll
    for (int it = 0; it < 4; it++) {
      int idx = it * 256 + tid;
      int r = idx >> 4, sl = idx & 15;
      uint4 vv = *(const uint4*)(A + (size_t)(row0 + r) * 128 + sl * 8);
      *(uint4*)(As + r * 128 + ((sl ^ (r & 7)) * 8)) = vv;
    }
  }

  #pragma unroll
  for (int t = 0; t < NT; t++) {
    __syncthreads();
    #pragma unroll
    for (int it = 0; it < 8; it++) {
      int idx = it * 256 + tid;
      int n = idx >> 4, sl = idx & 15;
      uint4 vv = *(const uint4*)(Bt + (size_t)(t * 128 + n) * 128 + sl * 8);
      *(uint4*)(Bs + n * 128 + ((sl ^ (n & 7)) * 8)) = vv;
    }
    __syncthreads();

    f32x4 acc[2][4] = {};
    #pragma unroll
    for (int kk = 0; kk < 4; kk++) {
      int sb = kk * 4 + (l >> 4);
      bf16x8 af[2], bfr[4];
      #pragma unroll
      for (int mi = 0; mi < 2; mi++) {
        int r = wr * 32 + mi * 16 + (l & 15);
        af[mi] = *(const bf16x8*)(As + r * 128 + ((sb ^ (r & 7)) * 8));
      }
      #pragma unroll
      for (int ni = 0; ni < 4; ni++) {
        int n = wc * 64 + ni * 16 + (l & 15);
        bfr[ni] = *(const bf16x8*)(Bs + n * 128 + ((sb ^ (n & 7)) * 8));
      }
      #pragma unroll
      for (int mi = 0; mi < 2; mi++)
        #pragma unroll
        for (int ni = 0; ni < 4; ni++)
          acc[mi][ni] = __builtin_amdgcn_mfma_f32_16x16x32_bf16(af[mi], bfr[ni], acc[mi][ni], 0, 0, 0);
    }

    #pragma unroll
    for (int mi = 0; mi < 2; mi++) {
      #pragma unroll
      for (int p = 0; p < 4; p++) {
        int r = row0 + wr * 32 + mi * 16 + (l >> 4) * 4 + p;
        #pragma unroll
        for (int ni = 0; ni < 4; ni++) {
          int cc = wc * 64 + ni * 16 + (l & 15);
          int c  = t * 128 + cc;
          float val = acc[mi][ni][p] + bias[c];
          if (RELU) val = fmaxf(val, 0.f);
          if (OUTMODE == 1) {
            ((unsigned short*)outp)[(size_t)r * (NT * 128) + c] = f2bf(val);
          } else {
            char* rowb = (char*)outp + (size_t)r * 512;
            if (t == 0)      *(unsigned short*)(rowb + cc * 2) = f2bf(val);
            else if (t == 1) *(unsigned char*)(rowb + 256 + cc) = f2fp8(val);
            else             *(unsigned char*)(rowb + 384 + cc) = f2fp8(val);
          }
        }
      }
    }
  }
}

// ---- Fused Wo-GEMM (inv-scaled A) + residual + LN2 + FFN1 ----------------
// blockIdx.y in {0,1}: both compute Wo+LN2 (redundant), each does 2 of the
// 4 FFN1 column tiles. y==0 also stores x1b.
__global__ __launch_bounds__(256) void k_woln2ffn1(const unsigned short* __restrict__ agg,
                                                   const unsigned short* __restrict__ Wot,
                                                   const float* __restrict__ dpart,
                                                   const float* __restrict__ bo,
                                                   const float* __restrict__ x,
                                                   const float* __restrict__ lng,
                                                   const float* __restrict__ lnb,
                                                   const unsigned short* __restrict__ W1t,
                                                   const float* __restrict__ b1,
                                                   unsigned short* __restrict__ x1b,
                                                   unsigned short* __restrict__ ffn1) {
  __shared__ char arena[49152];
  unsigned short* As   = (unsigned short*)arena;
  unsigned short* Bs   = (unsigned short*)(arena + 8192);
  unsigned short* Fs   = (unsigned short*)arena;
  unsigned short* BsW1 = (unsigned short*)(arena + 16384);
  __shared__ float lnS[64][2], lnSS[64][2], gS[128], bS[128], sinv[8];

  const int tid  = threadIdx.x;
  const int row0 = blockIdx.x * 64;
  const int by   = blockIdx.y;
  const int l    = tid & 63;
  const int w    = tid >> 6;
  const int wr   = w >> 1;
  const int wc   = w & 1;

  {
    int h = tid & 7;
    float s = 0.f;
    for (int r = tid >> 3; r < RBLK; r += 32) s += dpart[r * 8 + h];
    #pragma unroll
    for (int d = 8; d < 64; d <<= 1) s += __shfl_xor(s, d);
    if (tid < 128) { gS[tid] = lng[tid]; bS[tid] = lnb[tid]; }
    __shared__ float ws4[4][8];
    int lane = tid & 63, wv = tid >> 6;
    if (lane < 8) ws4[wv][lane] = s;
    __syncthreads();
    if (tid < 8) sinv[tid] = 1.0f / (ws4[0][tid] + ws4[1][tid] + ws4[2][tid] + ws4[3][tid]);
  }

  f32x4 acc[2][4] = {};
  for (int kc = 0; kc < 128; kc += 64) {
    __syncthreads();
    #pragma unroll
    for (int it = 0; it < 2; it++) {
      int idx = it * 256 + tid;
      int r = idx >> 3, s5 = idx & 7;
      uint4 vv = *(const uint4*)(agg + (size_t)(row0 + r) * 128 + kc + s5 * 8);
      float sc = sinv[(kc >> 4) + (s5 >> 1)];
      unsigned short tmp[8];
      const unsigned short* pv = (const unsigned short*)&vv;
      #pragma unroll
      for (int u = 0; u < 8; u++) tmp[u] = f2bf(bfs(pv[u]) * sc);
      *(uint4*)(As + r * 64 + ((s5 ^ (r & 7)) * 8)) = *(uint4*)tmp;
    }
    #pragma unroll
    for (int it = 0; it < 4; it++) {
      int idx = it * 256 + tid;
      int n = idx >> 3, s5 = idx & 7;
      uint4 vv = *(const uint4*)(Wot + (size_t)n * 128 + kc + s5 * 8);
      *(uint4*)(Bs + n * 64 + ((s5 ^ (n & 7)) * 8)) = vv;
    }
    __syncthreads();
    #pragma unroll
    for (int kk = 0; kk < 2; kk++) {
      int sb = kk * 4 + (l >> 4);
      bf16x8 af[2], bfr[4];
      #pragma unroll
      for (int mi = 0; mi < 2; mi++) {
        int r = wr * 32 + mi * 16 + (l & 15);
        af[mi] = *(const bf16x8*)(As + r * 64 + ((sb ^ (r & 7)) * 8));
      }
      #pragma unroll
      for (int ni = 0; ni < 4; ni++) {
        int n = wc * 64 + ni * 16 + (l & 15);
        bfr[ni] = *(const bf16x8*)(Bs + n * 64 + ((sb ^ (n & 7)) * 8));
      }
      #pragma unroll
      for (int mi = 0; mi < 2; mi++)
        #pragma unroll
        for (int ni = 0; ni < 4; ni++)
          acc[mi][ni] = __builtin_amdgcn_mfma_f32_16x16x32_bf16(af[mi], bfr[ni], acc[mi][ni], 0, 0, 0);
    }
  }

  #pragma unroll
  for (int mi = 0; mi < 2; mi++) {
    #pragma unroll
    for (int p = 0; p < 4; p++) {
      int lr = wr * 32 + mi * 16 + (l >> 4) * 4 + p;
      int r  = row0 + lr;
      float s = 0.f, ss = 0.f;
      #pragma unroll
      for (int ni = 0; ni < 4; ni++) {
        int c = wc * 64 + ni * 16 + (l & 15);
        float val = acc[mi][ni][p] + bo[c] + x[(size_t)r * 128 + c];
        acc[mi][ni][p] = val;
        s += val; ss += val * val;
      }
      #pragma unroll
      for (int d = 1; d < 16; d <<= 1) { s += __shfl_xor(s, d); ss += __shfl_xor(ss, d); }
      if ((l & 15) == 0) { lnS[lr][wc] = s; lnSS[lr][wc] = ss; }
    }
  }
  __syncthreads();
  #pragma unroll
  for (int mi = 0; mi < 2; mi++) {
    #pragma unroll
    for (int p = 0; p < 4; p++) {
      int lr = wr * 32 + mi * 16 + (l >> 4) * 4 + p;
      int r  = row0 + lr;
      float m   = (lnS[lr][0] + lnS[lr][1]) * (1.f / 128.f);
      float var = (lnSS[lr][0] + lnSS[lr][1]) * (1.f / 128.f) - m * m;
      float rstd = rsqrtf(var + 1e-5f);
      #pragma unroll
      for (int ni = 0; ni < 4; ni++) {
        int c = wc * 64 + ni * 16 + (l & 15);
        float val = acc[mi][ni][p];
        if (by == 0) x1b[(size_t)r * 128 + c] = f2bf(val);
        unsigned short xb = f2bf((val - m) * rstd * gS[c] + bS[c]);
        Fs[lr * 128 + (((c >> 3) ^ (lr & 7)) * 8) + (c & 7)] = xb;
      }
    }
  }

  for (int ti = 0; ti < 2; ti++) {
    int t = by * 2 + ti;
    __syncthreads();
    #pragma unroll
    for (int it = 0; it < 8; it++) {
      int idx = it * 256 + tid;
      int n = idx >> 4, sl = idx & 15;
      uint4 vv = *(const uint4*)(W1t + (size_t)(t * 128 + n) * 128 + sl * 8);
      *(uint4*)(BsW1 + n * 128 + ((sl ^ (n & 7)) * 8)) = vv;
    }
    __syncthreads();

    f32x4 acc2[2][4] = {};
    #pragma unroll
    for (int kk = 0; kk < 4; kk++) {
      int sb = kk * 4 + (l >> 4);
      bf16x8 af[2], bfr[4];
      #pragma unroll
      for (int mi = 0; mi < 2; mi++) {
        int r = wr * 32 + mi * 16 + (l & 15);
        af[mi] = *(const bf16x8*)(Fs + r * 128 + ((sb ^ (r & 7)) * 8));
      }
      #pragma unroll
      for (int ni = 0; ni < 4; ni++) {
        int n = wc * 64 + ni * 16 + (l & 15);
        bfr[ni] = *(const bf16x8*)(BsW1 + n * 128 + ((sb ^ (n & 7)) * 8));
      }
      #pragma unroll
      for (int mi = 0; mi < 2; mi++)
        #pragma unroll
        for (int ni = 0; ni < 4; ni++)
          acc2[mi][ni] = __builtin_amdgcn_mfma_f32_16x16x32_bf16(af[mi], bfr[ni], acc2[mi][ni], 0, 0, 0);
    }

    #pragma unroll
    for (int mi = 0; mi < 2; mi++) {
      #pragma unroll
      for (int p = 0; p < 4; p++) {
        int r = row0 + wr * 32 + mi * 16 + (l >> 4) * 4 + p;
        #pragma unroll
        for (int ni = 0; ni < 4; ni++) {
          int cc = wc * 64 + ni * 16 + (l & 15);
          int c  = t * 128 + cc;
          float val = fmaxf(acc2[mi][ni][p] + b1[c], 0.f);
          ffn1[(size_t)r * 512 + c] = f2bf(val);
        }
      }
    }
  }
}

// ------ Generic MFMA GEMM (kc loop). Used for FFN2. -----------------------
template <bool RELU, int RESMODE>
__global__ __launch_bounds__(256) void k_mgemm(const unsigned short* __restrict__ A,
                                               const unsigned short* __restrict__ Bt,
                                               const float* __restrict__ bias,
                                               const void* __restrict__ res,
                                               float* __restrict__ outp,
                                               int K, int Nc) {
  __shared__ unsigned short As[64 * 64];
  __shared__ unsigned short Bs[128 * 64];
  const int tid  = threadIdx.x;
  const int row0 = blockIdx.x * 64;
  const int c0   = blockIdx.y * 128;
  const int l    = tid & 63;
  const int w    = tid >> 6;
  const int wr   = w >> 1;
  const int wc   = w & 1;

  f32x4 acc[2][4] = {};

  for (int kc = 0; kc < K; kc += 64) {
    __syncthreads();
    #pragma unroll
    for (int it = 0; it < 2; it++) {
      int idx = it * 256 + tid;
      int r = idx >> 3, s = idx & 7;
      uint4 vv = *(const uint4*)(A + (size_t)(row0 + r) * K + kc + s * 8);
      *(uint4*)(As + r * 64 + ((s ^ (r & 7)) * 8)) = vv;
    }
    #pragma unroll
    for (int it = 0; it < 4; it++) {
      int idx = it * 256 + tid;
      int n = idx >> 3, s = idx & 7;
      uint4 vv = *(const uint4*)(Bt + (size_t)(c0 + n) * K + kc + s * 8);
      *(uint4*)(Bs + n * 64 + ((s ^ (n & 7)) * 8)) = vv;
    }
    __syncthreads();
    #pragma unroll
    for (int kk = 0; kk < 2; kk++) {
      int sb = kk * 4 + (l >> 4);
      bf16x8 af[2], bfr[4];
      #pragma unroll
      for (int mi = 0; mi < 2; mi++) {
        int r = wr * 32 + mi * 16 + (l & 15);
        af[mi] = *(const bf16x8*)(As + r * 64 + ((sb ^ (r & 7)) * 8));
      }
      #pragma unroll
      for (int ni = 0; ni < 4; ni++) {
        int n = wc * 64 + ni * 16 + (l & 15);
        bfr[ni] = *(const bf16x8*)(Bs + n * 64 + ((sb ^ (n & 7)) * 8));
      }
      #pragma unroll
      for (int mi = 0; mi < 2; mi++)
        #pragma unroll
        for (int ni = 0; ni < 4; ni++)
          acc[mi][ni] = __builtin_amdgcn_mfma_f32_16x16x32_bf16(af[mi], bfr[ni], acc[mi][ni], 0, 0, 0);
    }
  }

  #pragma unroll
  for (int mi = 0; mi < 2; mi++) {
    #pragma unroll
    for (int p = 0; p < 4; p++) {
      int r = row0 + wr * 32 + mi * 16 + (l >> 4) * 4 + p;
      #pragma unroll
      for (int ni = 0; ni < 4; ni++) {
        int c = c0 + wc * 64 + ni * 16 + (l & 15);
        float val = acc[mi][ni][p] + bias[c];
        if (RESMODE == 1) val += ((const float*)res)[(size_t)r * Nc + c];
        if (RESMODE == 2) val += bfs(((const unsigned short*)res)[(size_t)r * Nc + c]);
        if (RELU) val = fmaxf(val, 0.f);
        outp[(size_t)r * Nc + c] = val;
      }
    }
  }
}

// ------- CSR build: hist+rank (4 edges/thread) -> scan -> scatter ----------
__global__ __launch_bounds__(256) void k_histrank(const int* __restrict__ ei,
                                                  int* __restrict__ deg,
                                                  int* __restrict__ rank) {
  int base = blockIdx.x * 1024 + threadIdx.x;
  #pragma unroll
  for (int u = 0; u < 4; u++) {
    int e = base + u * 256;
    if (e < NEDGE) rank[e] = atomicAdd(&deg[ei[NEDGE + e]], 1);
  }
}

__global__ __launch_bounds__(256) void k_scan3a(const int* __restrict__ deg,
                                                int* __restrict__ bsum) {
  int i = blockIdx.x * 256 + threadIdx.x;
  int d = (i < NNODES) ? deg[i] : 0;
  #pragma unroll
  for (int s = 1; s < 64; s <<= 1) d += __shfl_xor(d, s);
  __shared__ int ws4[4];
  if ((threadIdx.x & 63) == 0) ws4[threadIdx.x >> 6] = d;
  __syncthreads();
  if (threadIdx.x == 0) bsum[blockIdx.x] = ws4[0] + ws4[1] + ws4[2] + ws4[3];
}

__global__ __launch_bounds__(256) void k_scan3c(const int* __restrict__ deg,
                                                const int* __restrict__ bsum,
                                                int* __restrict__ off) {
  const int t = threadIdx.x;
  __shared__ int ws4[4];
  __shared__ int sbase;
  {
    int lim = blockIdx.x < NBLK ? blockIdx.x : NBLK;
    int v = (t < lim) ? bsum[t] : 0;
    #pragma unroll
    for (int s = 1; s < 64; s <<= 1) v += __shfl_xor(v, s);
    if ((t & 63) == 0) ws4[t >> 6] = v;
    __syncthreads();
    if (t == 0) sbase = ws4[0] + ws4[1] + ws4[2] + ws4[3];
    __syncthreads();
  }
  int i = blockIdx.x * 256 + t;
  int d = (i < NNODES) ? deg[i] : 0;
  int lane = t & 63, wv = t >> 6;
  int incl = d;
  #pragma unroll
  for (int s = 1; s < 64; s <<= 1) { int o = __shfl_up(incl, s); if (lane >= s) incl += o; }
  __syncthreads();
  if (lane == 63) ws4[wv] = incl;
  __syncthreads();
  int base = sbase;
  for (int w2 = 0; w2 < wv; w2++) base += ws4[w2];
  int ex = base + incl - d;
  if (i < NNODES) off[i] = ex;
  if (i == 0) off[NNODES] = NEDGE;
}

__global__ __launch_bounds__(256) void k_scatter(const int* __restrict__ ei,
                                                 const int* __restrict__ off,
                                                 const int* __restrict__ rank,
                                                 int* __restrict__ srcs) {
  int base = blockIdx.x * 1024 + threadIdx.x;
  #pragma unroll
  for (int u = 0; u < 4; u++) {
    int e = base + u * 256;
    if (e < NEDGE) srcs[off[ei[NEDGE + e]] + rank[e]] = ei[e];
  }
}

// ------- Fused scores + aggregation: 1 wave/node, 1 lane = 1 (edge,head) ---
__global__ __launch_bounds__(256) void k_fused(const unsigned char* __restrict__ qkv,
                                               const int* __restrict__ off,
                                               const int* __restrict__ srcs,
                                               unsigned* __restrict__ U,
                                               float* __restrict__ hpart) {
  const int wave = threadIdx.x >> 6;
  const int lane = threadIdx.x & 63;
  const int n  = blockIdx.x * 4 + wave;
  const int g  = lane >> 3;   // edge slot 0..7
  const int c8 = lane & 7;    // head; channels c8*16 .. +15

  const uint4* qp = (const uint4*)(qkv + (size_t)n * 512 + c8 * 32);
  uint4 qa = qp[0], qb = qp[1];
  float qf[16];
  qf[0]=bflo(qa.x);  qf[1]=bfhi(qa.x);  qf[2]=bflo(qa.y);  qf[3]=bfhi(qa.y);
  qf[4]=bflo(qa.z);  qf[5]=bfhi(qa.z);  qf[6]=bflo(qa.w);  qf[7]=bfhi(qa.w);
  qf[8]=bflo(qb.x);  qf[9]=bfhi(qb.x);  qf[10]=bflo(qb.y); qf[11]=bfhi(qb.y);
  qf[12]=bflo(qb.z); qf[13]=bfhi(qb.z); qf[14]=bflo(qb.w); qf[15]=bfhi(qb.w);

  float acc[16];
  #pragma unroll
  for (int i = 0; i < 16; i++) acc[i] = 0.f;
  float lsum = 0.f;

  const int i0 = off[n], i1 = off[n + 1];
  if (i1 > i0) {
    int j0 = i0 + g; if (j0 >= i1) j0 = i1 - 1;
    int sA = srcs[j0];
    int sB;
    {
      int j1 = i0 + 8 + g;
      if (j1 >= i1) j1 = i1 - 1;
      sB = srcs[j1];
    }
    const uint4* kpA = (const uint4*)(qkv + (size_t)sA * 512 + 256 + c8 * 16);
    uint4 kw = kpA[0], vw = kpA[8];

    for (int jb = i0; jb < i1; jb += 8) {
      uint4 kc = kw, vc = vw;
      bool valid = jb + g < i1;
      if (jb + 8 < i1) {
        const uint4* kpB = (const uint4*)(qkv + (size_t)sB * 512 + 256 + c8 * 16);
        kw = kpB[0]; vw = kpB[8];
      }
      if (jb + 16 < i1) {
        int j2 = jb + 16 + g;
        if (j2 >= i1) j2 = i1 - 1;
        sB = srcs[j2];
      }
      float kf[16], vf[16];
      fp8x4d(kc.x, kf + 0); fp8x4d(kc.y, kf + 4); fp8x4d(kc.z, kf + 8); fp8x4d(kc.w, kf + 12);
      fp8x4d(vc.x, vf + 0); fp8x4d(vc.y, vf + 4); fp8x4d(vc.z, vf + 8); fp8x4d(vc.w, vf + 12);
      float p = 0.f;
      #pragma unroll
      for (int i = 0; i < 16; i++) p += qf[i] * kf[i];
      float w = valid ? __expf(p * 0.25f) : 0.f;
      lsum += w;
      #pragma unroll
      for (int i = 0; i < 16; i++) acc[i] += w * vf[i];
    }
  }

  #pragma unroll
  for (int d = 8; d < 64; d <<= 1) {
    #pragma unroll
    for (int i = 0; i < 16; i++) acc[i] += __shfl_xor(acc[i], d);
    lsum += __shfl_xor(lsum, d);
  }

  __shared__ float wsum[4][8];
  if (lane < 8) {
    wsum[wave][c8] = lsum;
    unsigned o[8];
    #pragma unroll
    for (int i = 0; i < 8; i++)
      o[i] = ((unsigned)f2bf(acc[2 * i + 1]) << 16) | f2bf(acc[2 * i]);
    uint4* up = (uint4*)(U + (size_t)n * 64 + c8 * 8);
    up[0] = make_uint4(o[0], o[1], o[2], o[3]);
    up[1] = make_uint4(o[4], o[5], o[6], o[7]);
  }
  __syncthreads();
  if (threadIdx.x < 8) {
    hpart[blockIdx.x * 8 + threadIdx.x] =
        wsum[0][threadIdx.x] + wsum[1][threadIdx.x] + wsum[2][threadIdx.x] + wsum[3][threadIdx.x];
  }
}

extern "C" void kernel_launch(void* const* d_in, const int* in_sizes, int n_in,
                              void* d_out, int out_size, void* d_ws, size_t ws_size,
                              hipStream_t stream) {
  const float* x    = (const float*)d_in[0];
  const int*   ei   = (const int*)d_in[1];
  const float* Wq   = (const float*)d_in[2];
  const float* bq   = (const float*)d_in[3];
  const float* Wk   = (const float*)d_in[4];
  const float* bk   = (const float*)d_in[5];
  const float* Wv   = (const float*)d_in[6];
  const float* bv   = (const float*)d_in[7];
  const float* Wo   = (const float*)d_in[8];
  const float* bo   = (const float*)d_in[9];
  const float* ln1g = (const float*)d_in[10];
  const float* ln1b = (const float*)d_in[11];
  const float* ln2g = (const float*)d_in[12];
  const float* ln2b = (const float*)d_in[13];
  const float* W1   = (const float*)d_in[14];
  const float* b1   = (const float*)d_in[15];
  const float* W2   = (const float*)d_in[16];
  const float* b2   = (const float*)d_in[17];
  float* out = (float*)d_out;

  char* p = (char*)d_ws;
  const size_t NCb = (size_t)NNODES * CCH * 2;                  // 10.24 MB
  unsigned char*  qkvb = (unsigned char*)p;  p += (size_t)NNODES * 512;      // 20.48 MB
  unsigned short* agg  = (unsigned short*)p; p += NCb;                        // U
  unsigned short* x1b  = (unsigned short*)p; p += NCb;                        // x1 bf16
  unsigned short* ffn1 = (unsigned short*)p; p += (size_t)NNODES * 512 * 2;   // 40.96 MB
  int* deg    = (int*)p;                     p += (size_t)NNODES * 4 + 256;
  int* off    = (int*)p;                     p += (size_t)(NNODES + 1) * 4 + 256;
  int* rank   = (int*)p;                     p += (size_t)NEDGE * 4;
  int* srcs   = (int*)p;                     p += (size_t)NEDGE * 4;
  int* bsum   = (int*)p;                     p += 256 * 4;
  float* hpart = (float*)p;                  p += (size_t)FBLK * 8 * 4;
  float* dpart = (float*)p;                  p += (size_t)RBLK * 8 * 4 + 256;
  float* bqkv  = (float*)p;                  p += 384 * 4 + 256;
  unsigned short* Wqkvt = (unsigned short*)p; p += (size_t)384 * CCH * 2;
  unsigned short* Wot   = (unsigned short*)p; p += (size_t)CCH * CCH * 2;
  unsigned short* W1t   = (unsigned short*)p; p += (size_t)CCH * 4 * CCH * 2;
  unsigned short* W2t   = (unsigned short*)p; p += (size_t)CCH * 4 * CCH * 2;

  dim3 blk(256);
  dim3 gM(NNODES / 64, 1);
  dim3 gW(NNODES / 64, 2);

  // 1. weight prep (incl. Wot) + deg zeroing
  k_wprep_all<<<770, blk, 0, stream>>>(Wq, Wk, Wv, W1, W2, Wo, bq, bk, bv,
                                       Wqkvt, W1t, W2t, Wot, bqkv, deg);

  // 2-5. CSR build (4 edges/thread)
  k_histrank<<<EBLK, blk, 0, stream>>>(ei, deg, rank);
  k_scan3a<<<NBLK, blk, 0, stream>>>(deg, bsum);
  k_scan3c<<<NBLK, blk, 0, stream>>>(deg, bsum, off);
  k_scatter<<<EBLK, blk, 0, stream>>>(ei, off, rank, srcs);

  // 6. LN1 + packed QKV GEMM fused (q bf16 | k fp8 | v fp8, 512B rows)
  k_gemm128<3, 2, true, false><<<gM, blk, 0, stream>>>(x, Wqkvt, bqkv,
                                                       ln1g, ln1b, qkvb);

  // 7-8. fused scores+aggregation, parallel denominator reduce
  k_fused<<<FBLK, blk, 0, stream>>>(qkvb, off, srcs, (unsigned*)agg, hpart);
  k_reduce_part<<<RBLK, blk, 0, stream>>>(hpart, dpart);

  // 9. fused Wo(inv-scaled A) + residual + LN2 + FFN1, y-split over 2 tiles
  k_woln2ffn1<<<gW, blk, 0, stream>>>(agg, Wot, dpart, bo, x, ln2g, ln2b,
                                      W1t, b1, x1b, ffn1);

  // 10. FFN2 (+bf16 residual x1) -> d_out fp32
  k_mgemm<false, 2><<<gM, blk, 0, stream>>>(ffn1, W2t, b2, x1b, out,
                                            4 * CCH, CCH);
}